// Round 9
// baseline (2370.545 us; speedup 1.0000x reference)
//
#include <hip/hip_runtime.h>
#include <math.h>
#include <stdint.h>

#define T_STEPS 100
#define B_DIM 128
#define I_DIM 1024
#define H_DIM 4096
#define O_DIM 512
#define T_CHUNK 20
#define HS_RING 21
#define HS_SLOT ((size_t)8*128*512)   // f16 per t-slot (8 m16-tiles x 128 kc x 512)

typedef _Float16 f16x8 __attribute__((ext_vector_type(8)));
typedef _Float16 f16x4 __attribute__((ext_vector_type(4)));
typedef float    f32x4 __attribute__((ext_vector_type(4)));

#define AS1 __attribute__((address_space(1)))
#define AS3 __attribute__((address_space(3)))

// Async global->LDS, 16B/lane. LDS dest is wave-uniform base + lane*16 (m104),
// which exactly matches the 1KB fragment-block layout (64 lanes x 16B).
__device__ __forceinline__ void gload_lds16(const _Float16* g, _Float16* l){
  __builtin_amdgcn_global_load_lds(
      (const AS1 unsigned*)(uintptr_t)g,
      (AS3 unsigned*)(unsigned)(uintptr_t)l, 16, 0, 0);
}

__device__ __forceinline__ unsigned fmap(float f){
  unsigned u = __float_as_uint(f);
  return (u & 0x80000000u) ? ~u : (u | 0x80000000u);
}
__device__ __forceinline__ float funmap(unsigned m){
  unsigned u = (m & 0x80000000u) ? (m & 0x7FFFFFFFu) : ~m;
  return __uint_as_float(u);
}
__device__ __forceinline__ float vth_of(unsigned m){
  return 0.3f * tanhf(0.3f * funmap(m));
}

__global__ __launch_bounds__(256) void init_kernel(float* hv, unsigned* hmaxA)
{
  int i = blockIdx.x * 256 + threadIdx.x;
  if (i < B_DIM*H_DIM) hv[i] = 0.f;
  if (i < 128) hmaxA[i] = (i==0) ? 0x80000000u : fmap(-3.0e38f); // slot0 = max(0)
}

// spike_data [B][I][T] fp32 -> fragment-tiled f16 hi/lo of (x*2048), chunk of 20 t.
__global__ __launch_bounds__(256) void prep_x(const float* __restrict__ sp,
                                              _Float16* __restrict__ Ahi,
                                              _Float16* __restrict__ Alo, int t0)
{
  __shared__ float tile[32][16][10];
  const int b16 = blockIdx.x, kc = blockIdx.y, tz = blockIdx.z;
  for (int e = threadIdx.x; e < 5120; e += 256){
    int tt = e % 10, row = e / 10;
    int bb = row >> 5, ii = row & 31;
    tile[ii][bb][tt] =
      sp[((size_t)(b16*16+bb)*I_DIM + kc*32 + ii)*T_STEPS + t0 + tz*10 + tt];
  }
  __syncthreads();
  for (int u = threadIdx.x; u < 640; u += 256){
    int tl = u >> 6, l = u & 63, kg = l >> 4, r = l & 15;
    f16x8 hi, lo;
    #pragma unroll
    for (int e=0;e<8;e++){
      float x = tile[kg*8+e][r][tl] * 2048.f;
      _Float16 h = (_Float16)x;
      hi[e] = h;
      lo[e] = (_Float16)(x - (float)h);
    }
    int t_local = tz*10 + tl;
    size_t off = ((size_t)(t_local*8 + b16)*32 + kc)*512 + kg*128 + r*8;
    *(f16x8*)(Ahi + off) = hi;
    *(f16x8*)(Alo + off) = lo;
  }
}

// Wh [H][I] and Wo [O][H] fp32 -> FB-tiled f16 hi/lo of (w*256), one launch.
// Blocks 0..255: Wh (n16 = blk). Blocks 256..287: Wo (n16 = blk-256).
__global__ __launch_bounds__(256) void prep_weights(
    const float* __restrict__ Wh, const float* __restrict__ Wo,
    _Float16* __restrict__ WHhi, _Float16* __restrict__ WHlo,
    _Float16* __restrict__ WOhi, _Float16* __restrict__ WOlo)
{
  const int blk = blockIdx.x;
  if (blk < 256){
    const int n16 = blk;
    for (int u = threadIdx.x; u < 2048; u += 256){
      int kc = u >> 6, l = u & 63, kg = l >> 4, r = l & 15;
      const float* src = Wh + (size_t)(n16*16 + r)*I_DIM + kc*32 + kg*8;
      f16x8 hi, lo;
      #pragma unroll
      for (int e=0;e<8;e++){
        float x = src[e] * 256.f;
        _Float16 h = (_Float16)x;
        hi[e] = h; lo[e] = (_Float16)(x - (float)h);
      }
      size_t off = ((size_t)n16*32 + kc)*512 + kg*128 + r*8;
      *(f16x8*)(WHhi + off) = hi;
      *(f16x8*)(WHlo + off) = lo;
    }
  } else {
    const int n16 = blk - 256;
    for (int u = threadIdx.x; u < 8192; u += 256){
      int kc = u >> 6, l = u & 63, kg = l >> 4, r = l & 15;
      const float* src = Wo + (size_t)(n16*16 + r)*H_DIM + kc*32 + kg*8;
      f16x8 hi, lo;
      #pragma unroll
      for (int e=0;e<8;e++){
        float x = src[e] * 256.f;
        _Float16 h = (_Float16)x;
        hi[e] = h; lo[e] = (_Float16)(x - (float)h);
      }
      size_t off = ((size_t)(n16*128 + kc))*512 + kg*128 + r*8;
      *(f16x8*)(WOhi + off) = hi;
      *(f16x8*)(WOlo + off) = lo;
    }
  }
}

// Batched GEMM1 (chunk of 20 t): G = XT @ Wh^T via fp16x3 exact-split MFMA.
// K-loop: async global_load_lds double-buffer, ONE barrier per kc (m97 form).
__global__ __launch_bounds__(256, 2) void gemm1_mfma(
    const _Float16* __restrict__ Ahi, const _Float16* __restrict__ Alo,
    const _Float16* __restrict__ Bhi, const _Float16* __restrict__ Blo,
    float* __restrict__ G)
{
  __shared__ __align__(16) _Float16 lds[2][4][8][512];   // 64 KB, 2 blocks/CU
  const int tid = threadIdx.x, wave = tid>>6, lane = tid&63;
  const int bn = blockIdx.x, bm = blockIdx.y;
  const int wm = wave>>1, wn = wave&1;

  const _Float16* srcbase = (wave==0)?Ahi:(wave==1)?Alo:(wave==2)?Bhi:Blo;
  const int r16b = ((wave<2) ? bm : bn)*8;
  const _Float16* gsrc = srcbase + (size_t)r16b*32*512 + lane*8;

  f32x4 acc[16];
  #pragma unroll
  for (int i=0;i<16;i++) acc[i] = (f32x4){0.f,0.f,0.f,0.f};

  // stage kc=0 into buffer 0
  #pragma unroll
  for (int q=0;q<8;q++)
    gload_lds16(gsrc + (size_t)q*32*512, &lds[0][wave][q][0]);

  for (int kc=0;kc<32;kc++){
    __syncthreads();              // vmcnt(0) drain + barrier: buf[kc&1] ready
    if (kc < 31){                 // async prefetch kc+1; flies during compute
      #pragma unroll
      for (int q=0;q<8;q++)
        gload_lds16(gsrc + ((size_t)q*32 + kc+1)*512, &lds[(kc+1)&1][wave][q][0]);
    }
    const int cb = kc&1;
    f16x8 fAh[4], fAl[4], fBh[4], fBl[4];
    #pragma unroll
    for (int i=0;i<4;i++){
      fAh[i] = *(const f16x8*)&lds[cb][0][wm*4+i][lane*8];
      fAl[i] = *(const f16x8*)&lds[cb][1][wm*4+i][lane*8];
      fBh[i] = *(const f16x8*)&lds[cb][2][wn*4+i][lane*8];
      fBl[i] = *(const f16x8*)&lds[cb][3][wn*4+i][lane*8];
    }
    #pragma unroll
    for (int i=0;i<4;i++)
      #pragma unroll
      for (int j=0;j<4;j++)
        acc[i*4+j] = __builtin_amdgcn_mfma_f32_16x16x32_f16(fAh[i], fBh[j], acc[i*4+j], 0,0,0);
    #pragma unroll
    for (int i=0;i<4;i++)
      #pragma unroll
      for (int j=0;j<4;j++)
        acc[i*4+j] = __builtin_amdgcn_mfma_f32_16x16x32_f16(fAh[i], fBl[j], acc[i*4+j], 0,0,0);
    #pragma unroll
    for (int i=0;i<4;i++)
      #pragma unroll
      for (int j=0;j<4;j++)
        acc[i*4+j] = __builtin_amdgcn_mfma_f32_16x16x32_f16(fAl[i], fBh[j], acc[i*4+j], 0,0,0);
  }
  const int colw = lane&15, quad = lane>>4;
  const float sc = 1.f/(2048.f*256.f);
  float* eds = (float*)lds + wave*2048;
  __syncthreads();
  #pragma unroll
  for (int ih=0; ih<2; ih++){
    #pragma unroll
    for (int il=0; il<2; il++){
      int i = ih*2+il;
      #pragma unroll
      for (int j=0;j<4;j++)
        #pragma unroll
        for (int r=0;r<4;r++)
          eds[(il*16 + quad*4 + r)*64 + j*16 + colw] = acc[i*4+j][r]*sc;
    }
    #pragma unroll
    for (int rr8=0; rr8<8; rr8++){
      int row = rr8*4 + quad;
      float4 v = *(float4*)&eds[row*64 + colw*4];
      int m = bm*128 + wm*64 + ih*32 + row;
      int n = bn*128 + wn*64 + colw*4;
      *(float4*)&G[(size_t)m*H_DIM + n] = v;
    }
  }
}

// Sequential hv step t: emits hs_{t-1} (f16, fragment-tiled into ring slot),
// then hv_t = (hv>vth?0:0.5hv) + G_t, block max -> hmaxA[t+1].
// Reduction: wave shfl + red[4] + ONE barrier (was an 8-barrier tree).
__global__ __launch_bounds__(256) void hv_step(
    const float* __restrict__ Gs, float* __restrict__ hv,
    _Float16* __restrict__ hs_slot,
    const unsigned* __restrict__ hmax_t, unsigned* __restrict__ hmax_n, int t)
{
  __shared__ float red[4];
  const int tid = threadIdx.x, lane = tid&63, wv = tid>>6;
  const int gid = blockIdx.x*256 + tid;     // 0..131071 (f4 index)
  const int b = gid >> 10, h0 = (gid & 1023) << 2;
  const float vth = vth_of(*hmax_t);
  float4 h = *(const float4*)(hv + (size_t)gid*4);

  if (t > 0){   // hs_{t-1} = hv_{t-1} > vth(max hv_{t-1})
    const int kc = h0>>5, kg=(h0>>3)&3, e=h0&7, r=b&15, m16l=b>>4;
    f16x4 s;
    s[0]=(h.x>vth)?(_Float16)1:(_Float16)0; s[1]=(h.y>vth)?(_Float16)1:(_Float16)0;
    s[2]=(h.z>vth)?(_Float16)1:(_Float16)0; s[3]=(h.w>vth)?(_Float16)1:(_Float16)0;
    *(f16x4*)(hs_slot + ((size_t)m16l*128 + kc)*512 + kg*128 + r*8 + e) = s;
  }
  if (t < T_STEPS){
    float4 g = *(const float4*)(Gs + (size_t)gid*4);
    float4 o;
    o.x = (h.x>vth ? 0.f : 0.5f*h.x) + g.x;
    o.y = (h.y>vth ? 0.f : 0.5f*h.y) + g.y;
    o.z = (h.z>vth ? 0.f : 0.5f*h.z) + g.z;
    o.w = (h.w>vth ? 0.f : 0.5f*h.w) + g.w;
    *(float4*)(hv + (size_t)gid*4) = o;
    float lmax = fmaxf(fmaxf(o.x,o.y),fmaxf(o.z,o.w));
    #pragma unroll
    for (int off=32; off>0; off>>=1) lmax = fmaxf(lmax, __shfl_down(lmax, off));
    if (lane==0) red[wv] = lmax;
    __syncthreads();
    if (tid==0){
      float m = fmaxf(fmaxf(red[0],red[1]),fmaxf(red[2],red[3]));
      atomicMax(hmax_n, fmap(m));
    }
  }
}

// Batched GEMM2 for one chunk: OG[s] = HS[s] @ Wo^T (A exact f16, B hi/lo).
__global__ __launch_bounds__(256) void gemm2_mfma(
    const _Float16* __restrict__ HS,
    const _Float16* __restrict__ WoHi, const _Float16* __restrict__ WoLo,
    float* __restrict__ OG, int c)
{
  __shared__ float eds[4][2048];
  const int tid = threadIdx.x, wave = tid>>6, lane = tid&63;
  const int bn = blockIdx.x, bm = blockIdx.y;
  const int s = c*T_CHUNK + bm, ring = s % HS_RING;
  const int wm = wave>>1, wn = wave&1;

  const _Float16* Ab  = HS + ((size_t)(ring*8 + wm*4)*128)*512 + lane*8;
  const _Float16* Bhb = WoHi + ((size_t)(bn*8 + wn*4)*128)*512 + lane*8;
  const _Float16* Blb = WoLo + ((size_t)(bn*8 + wn*4)*128)*512 + lane*8;

  f32x4 acc[16];
  #pragma unroll
  for (int i=0;i<16;i++) acc[i] = (f32x4){0.f,0.f,0.f,0.f};

  int4 ra[4], rh[4], rl[4];
  #pragma unroll
  for (int q=0;q<4;q++){
    ra[q] = *(const int4*)(Ab  + (size_t)q*128*512);
    rh[q] = *(const int4*)(Bhb + (size_t)q*128*512);
    rl[q] = *(const int4*)(Blb + (size_t)q*128*512);
  }
  for (int kc=0;kc<128;kc++){
    f16x8 fA[4], fH[4], fL[4];
    #pragma unroll
    for (int q=0;q<4;q++){
      fA[q] = *(f16x8*)&ra[q]; fH[q] = *(f16x8*)&rh[q]; fL[q] = *(f16x8*)&rl[q];
    }
    if (kc < 127){
      #pragma unroll
      for (int q=0;q<4;q++){
        ra[q] = *(const int4*)(Ab  + ((size_t)q*128 + kc+1)*512);
        rh[q] = *(const int4*)(Bhb + ((size_t)q*128 + kc+1)*512);
        rl[q] = *(const int4*)(Blb + ((size_t)q*128 + kc+1)*512);
      }
    }
    #pragma unroll
    for (int i=0;i<4;i++)
      #pragma unroll
      for (int j=0;j<4;j++)
        acc[i*4+j] = __builtin_amdgcn_mfma_f32_16x16x32_f16(fA[i], fH[j], acc[i*4+j], 0,0,0);
    #pragma unroll
    for (int i=0;i<4;i++)
      #pragma unroll
      for (int j=0;j<4;j++)
        acc[i*4+j] = __builtin_amdgcn_mfma_f32_16x16x32_f16(fA[i], fL[j], acc[i*4+j], 0,0,0);
  }
  const int colw = lane&15, quad = lane>>4;
  const float sc = 1.f/256.f;
  #pragma unroll
  for (int ih=0; ih<2; ih++){
    #pragma unroll
    for (int il=0; il<2; il++){
      int i = ih*2+il;
      #pragma unroll
      for (int j=0;j<4;j++)
        #pragma unroll
        for (int r=0;r<4;r++)
          eds[wave][(il*16 + quad*4 + r)*64 + j*16 + colw] = acc[i*4+j][r]*sc;
    }
    #pragma unroll
    for (int rr8=0; rr8<8; rr8++){
      int row = rr8*4 + quad;
      float4 v = *(float4*)&eds[wave][row*64 + colw*4];
      int m = s*128 + wm*64 + ih*32 + row;
      int n = bn*128 + wn*64 + colw*4;
      *(float4*)&OG[(size_t)m*O_DIM + n] = v;
    }
  }
}

// Whole ov recurrence in ONE 1024-thread block. v3:
//  - spike counts accumulated IN REGISTERS (cnt[16] byte-packed, max 100<255)
//    -> no bits stores, no count_kernel.
//  - ONE barrier per step: wave shfl-reduce -> red[t&1][16] (double-buffered,
//    so no second barrier) -> every thread redundantly computes max+tanh.
//  - quarter-depth issue-before-consume load pipeline (Q0 of t+1 issued before
//    the reduction tail; the barrier's vmcnt drain completes it).
__global__ __launch_bounds__(1024, 4) void ov_chain(const float* __restrict__ OG,
                                                    float* __restrict__ out)
{
  __shared__ float red[2][16];
  const int tid = threadIdx.x, lane = tid&63, wv = tid>>6;
  float ov[64];
  unsigned cnt[16];
  #pragma unroll
  for (int e=0;e<64;e++) ov[e]=0.f;
  #pragma unroll
  for (int q=0;q<16;q++) cnt[q]=0u;

  const float* base = OG + tid*4;      // slice layout: float4 idx = q*1024+tid
  float4 A[4], Bq[4];
  #pragma unroll
  for (int p=0;p<4;p++) A[p] = *(const float4*)(base + p*4096);  // Q0 of t=0

  for (int t=0;t<T_STEPS;t++){
    const float* cur = base + (size_t)t*65536;
    float lmax = -3.0e38f;
    // phase 0: issue Q1 -> Bq, consume A (Q0)
    #pragma unroll
    for (int p=0;p<4;p++) Bq[p] = *(const float4*)(cur + (4+p)*4096);
    #pragma unroll
    for (int p=0;p<4;p++){
      int e = p*4;
      ov[e+0]+=A[p].x; ov[e+1]+=A[p].y; ov[e+2]+=A[p].z; ov[e+3]+=A[p].w;
      lmax = fmaxf(lmax, fmaxf(fmaxf(ov[e+0],ov[e+1]),fmaxf(ov[e+2],ov[e+3])));
    }
    // phase 1: issue Q2 -> A, consume Bq (Q1)
    #pragma unroll
    for (int p=0;p<4;p++) A[p] = *(const float4*)(cur + (8+p)*4096);
    #pragma unroll
    for (int p=0;p<4;p++){
      int e = 16 + p*4;
      ov[e+0]+=Bq[p].x; ov[e+1]+=Bq[p].y; ov[e+2]+=Bq[p].z; ov[e+3]+=Bq[p].w;
      lmax = fmaxf(lmax, fmaxf(fmaxf(ov[e+0],ov[e+1]),fmaxf(ov[e+2],ov[e+3])));
    }
    // phase 2: issue Q3 -> Bq, consume A (Q2)
    #pragma unroll
    for (int p=0;p<4;p++) Bq[p] = *(const float4*)(cur + (12+p)*4096);
    #pragma unroll
    for (int p=0;p<4;p++){
      int e = 32 + p*4;
      ov[e+0]+=A[p].x; ov[e+1]+=A[p].y; ov[e+2]+=A[p].z; ov[e+3]+=A[p].w;
      lmax = fmaxf(lmax, fmaxf(fmaxf(ov[e+0],ov[e+1]),fmaxf(ov[e+2],ov[e+3])));
    }
    // phase 3: issue Q0(t+1) -> A (drains at the barrier), consume Bq (Q3)
    if (t+1 < T_STEPS){
      #pragma unroll
      for (int p=0;p<4;p++) A[p] = *(const float4*)(cur + 65536 + p*4096);
    }
    #pragma unroll
    for (int p=0;p<4;p++){
      int e = 48 + p*4;
      ov[e+0]+=Bq[p].x; ov[e+1]+=Bq[p].y; ov[e+2]+=Bq[p].z; ov[e+3]+=Bq[p].w;
      lmax = fmaxf(lmax, fmaxf(fmaxf(ov[e+0],ov[e+1]),fmaxf(ov[e+2],ov[e+3])));
    }
    // block max -> threshold: ONE barrier, redundant tanh on all threads
    #pragma unroll
    for (int off=32; off>0; off>>=1) lmax = fmaxf(lmax, __shfl_down(lmax, off));
    if (lane==0) red[t&1][wv] = lmax;
    __syncthreads();
    float m = red[t&1][0];
    #pragma unroll
    for (int w=1;w<16;w++) m = fmaxf(m, red[t&1][w]);
    const float vt = 0.3f * tanhf(0.3f * m);
    #pragma unroll
    for (int q=0;q<16;q++)
      #pragma unroll
      for (int c=0;c<4;c++){
        int e = q*4+c;
        bool os = ov[e] > vt;
        cnt[q] += os ? (1u<<(c*8)) : 0u;
        ov[e] = os ? 0.f : 0.5f*ov[e];
      }
  }
  #pragma unroll
  for (int q=0;q<16;q++){
    float4 o;
    o.x = (float)( cnt[q]        & 0xffu);
    o.y = (float)((cnt[q] >> 8)  & 0xffu);
    o.z = (float)((cnt[q] >> 16) & 0xffu);
    o.w = (float)((cnt[q] >> 24) & 0xffu);
    *(float4*)(out + ((size_t)q*1024 + tid)*4) = o;
  }
}

extern "C" void kernel_launch(void* const* d_in, const int* in_sizes, int n_in,
                              void* d_out, int out_size, void* d_ws, size_t ws_size,
                              hipStream_t stream) {
  const float* spike = (const float*)d_in[0];
  const float* Wh    = (const float*)d_in[5];   // [H, I]
  const float* Wo    = (const float*)d_in[6];   // [O, H]
  float* out = (float*)d_out;

  char* ws = (char*)d_ws;
  size_t off = 0;
  _Float16* XAhi = (_Float16*)(ws+off); off += (size_t)T_CHUNK*B_DIM*I_DIM*2;
  _Float16* XAlo = (_Float16*)(ws+off); off += (size_t)T_CHUNK*B_DIM*I_DIM*2;
  _Float16* WHhi = (_Float16*)(ws+off); off += (size_t)H_DIM*I_DIM*2;
  _Float16* WHlo = (_Float16*)(ws+off); off += (size_t)H_DIM*I_DIM*2;
  _Float16* WOhi = (_Float16*)(ws+off); off += (size_t)O_DIM*H_DIM*2;
  _Float16* WOlo = (_Float16*)(ws+off); off += (size_t)O_DIM*H_DIM*2;
  float* G  = (float*)(ws+off);         off += (size_t)T_CHUNK*B_DIM*H_DIM*4;
  float* hv = (float*)(ws+off);         off += (size_t)B_DIM*H_DIM*4;
  _Float16* HS = (_Float16*)(ws+off);   off += (size_t)HS_RING*HS_SLOT*2;
  float* OG = (float*)(ws+off);         off += (size_t)T_STEPS*B_DIM*O_DIM*4;
  unsigned* hmaxA = (unsigned*)(ws+off); off += 128*4;
  (void)ws_size; (void)in_sizes; (void)n_in; (void)out_size;

  init_kernel<<<(B_DIM*H_DIM+255)/256, 256, 0, stream>>>(hv, hmaxA);
  prep_weights<<<288, 256, 0, stream>>>(Wh, Wo, WHhi, WHlo, WOhi, WOlo);

  for (int c = 0; c < T_STEPS/T_CHUNK; c++){
    prep_x<<<dim3(8,32,2), 256, 0, stream>>>(spike, XAhi, XAlo, c*T_CHUNK);
    gemm1_mfma<<<dim3(32, T_CHUNK), 256, 0, stream>>>(XAhi, XAlo, WHhi, WHlo, G);
    for (int j = 0; j < T_CHUNK; j++){
      int t = c*T_CHUNK + j;
      int ring = (t == 0) ? (HS_RING-1) : ((t-1) % HS_RING);
      hv_step<<<512, 256, 0, stream>>>(
          G + (size_t)j*B_DIM*H_DIM, hv, HS + (size_t)ring*HS_SLOT,
          hmaxA + t, hmaxA + t + 1, t);
      if (j == 0 && c > 0)
        gemm2_mfma<<<dim3(4, T_CHUNK), 256, 0, stream>>>(HS, WOhi, WOlo, OG, c-1);
    }
  }
  // hs_99 tail (t=100: emit-only), then last gemm2 chunk, then the ov chain.
  hv_step<<<512, 256, 0, stream>>>(
      G, hv, HS + (size_t)((T_STEPS-1) % HS_RING)*HS_SLOT,
      hmaxA + T_STEPS, hmaxA + T_STEPS, T_STEPS);
  gemm2_mfma<<<dim3(4, T_CHUNK), 256, 0, stream>>>(HS, WOhi, WOlo, OG, T_STEPS/T_CHUNK - 1);
  ov_chain<<<1, 1024, 0, stream>>>(OG, out);
}

// Round 10
// 2028.593 us; speedup vs baseline: 1.1686x; 1.1686x over previous
//
#include <hip/hip_runtime.h>
#include <math.h>
#include <stdint.h>

#define T_STEPS 100
#define B_DIM 128
#define I_DIM 1024
#define H_DIM 4096
#define O_DIM 512
#define T_CHUNK 20
#define HS_RING 21
#define HS_SLOT ((size_t)8*128*512)   // f16 per t-slot (8 m16-tiles x 128 kc x 512)
#define OV_LAG 21                     // ov step t' rides on hv launch t = t'+21

typedef _Float16 f16x8 __attribute__((ext_vector_type(8)));
typedef _Float16 f16x4 __attribute__((ext_vector_type(4)));
typedef float    f32x4 __attribute__((ext_vector_type(4)));

#define AS1 __attribute__((address_space(1)))
#define AS3 __attribute__((address_space(3)))

// Async global->LDS, 16B/lane. LDS dest is wave-uniform base + lane*16,
// which exactly matches the 1KB fragment-block layout (64 lanes x 16B).
__device__ __forceinline__ void gload_lds16(const _Float16* g, _Float16* l){
  __builtin_amdgcn_global_load_lds(
      (const AS1 unsigned*)(uintptr_t)g,
      (AS3 unsigned*)(unsigned)(uintptr_t)l, 16, 0, 0);
}

__device__ __forceinline__ unsigned fmap(float f){
  unsigned u = __float_as_uint(f);
  return (u & 0x80000000u) ? ~u : (u | 0x80000000u);
}
__device__ __forceinline__ float funmap(unsigned m){
  unsigned u = (m & 0x80000000u) ? (m & 0x7FFFFFFFu) : ~m;
  return __uint_as_float(u);
}
__device__ __forceinline__ float vth_of(unsigned m){
  return 0.3f * tanhf(0.3f * funmap(m));
}

__global__ __launch_bounds__(256) void init_kernel(float* hv, float* ovs,
                                                   uint32_t* cnt32,
                                                   unsigned* hmaxA, unsigned* omaxA)
{
  int i = blockIdx.x * 256 + threadIdx.x;
  if (i < B_DIM*H_DIM) hv[i] = 0.f;
  if (i < B_DIM*O_DIM) ovs[i] = 0.f;
  if (i < B_DIM*O_DIM/4) cnt32[i] = 0u;
  if (i < 128){
    // slot0 = "max of zero state" -> 0 -> vth 0 -> spike(0>0)=0
    unsigned v = (i==0) ? 0x80000000u : fmap(-3.0e38f);
    hmaxA[i] = v; omaxA[i] = v;
  }
}

// spike_data [B][I][T] fp32 -> fragment-tiled f16 hi/lo of (x*2048), chunk of 20 t.
__global__ __launch_bounds__(256) void prep_x(const float* __restrict__ sp,
                                              _Float16* __restrict__ Ahi,
                                              _Float16* __restrict__ Alo, int t0)
{
  __shared__ float tile[32][16][10];
  const int b16 = blockIdx.x, kc = blockIdx.y, tz = blockIdx.z;
  for (int e = threadIdx.x; e < 5120; e += 256){
    int tt = e % 10, row = e / 10;
    int bb = row >> 5, ii = row & 31;
    tile[ii][bb][tt] =
      sp[((size_t)(b16*16+bb)*I_DIM + kc*32 + ii)*T_STEPS + t0 + tz*10 + tt];
  }
  __syncthreads();
  for (int u = threadIdx.x; u < 640; u += 256){
    int tl = u >> 6, l = u & 63, kg = l >> 4, r = l & 15;
    f16x8 hi, lo;
    #pragma unroll
    for (int e=0;e<8;e++){
      float x = tile[kg*8+e][r][tl] * 2048.f;
      _Float16 h = (_Float16)x;
      hi[e] = h;
      lo[e] = (_Float16)(x - (float)h);
    }
    int t_local = tz*10 + tl;
    size_t off = ((size_t)(t_local*8 + b16)*32 + kc)*512 + kg*128 + r*8;
    *(f16x8*)(Ahi + off) = hi;
    *(f16x8*)(Alo + off) = lo;
  }
}

// Wh [H][I] and Wo [O][H] fp32 -> FB-tiled f16 hi/lo of (w*256), one launch.
__global__ __launch_bounds__(256) void prep_weights(
    const float* __restrict__ Wh, const float* __restrict__ Wo,
    _Float16* __restrict__ WHhi, _Float16* __restrict__ WHlo,
    _Float16* __restrict__ WOhi, _Float16* __restrict__ WOlo)
{
  const int blk = blockIdx.x;
  if (blk < 256){
    const int n16 = blk;
    for (int u = threadIdx.x; u < 2048; u += 256){
      int kc = u >> 6, l = u & 63, kg = l >> 4, r = l & 15;
      const float* src = Wh + (size_t)(n16*16 + r)*I_DIM + kc*32 + kg*8;
      f16x8 hi, lo;
      #pragma unroll
      for (int e=0;e<8;e++){
        float x = src[e] * 256.f;
        _Float16 h = (_Float16)x;
        hi[e] = h; lo[e] = (_Float16)(x - (float)h);
      }
      size_t off = ((size_t)n16*32 + kc)*512 + kg*128 + r*8;
      *(f16x8*)(WHhi + off) = hi;
      *(f16x8*)(WHlo + off) = lo;
    }
  } else {
    const int n16 = blk - 256;
    for (int u = threadIdx.x; u < 8192; u += 256){
      int kc = u >> 6, l = u & 63, kg = l >> 4, r = l & 15;
      const float* src = Wo + (size_t)(n16*16 + r)*H_DIM + kc*32 + kg*8;
      f16x8 hi, lo;
      #pragma unroll
      for (int e=0;e<8;e++){
        float x = src[e] * 256.f;
        _Float16 h = (_Float16)x;
        hi[e] = h; lo[e] = (_Float16)(x - (float)h);
      }
      size_t off = ((size_t)(n16*128 + kc))*512 + kg*128 + r*8;
      *(f16x8*)(WOhi + off) = hi;
      *(f16x8*)(WOlo + off) = lo;
    }
  }
}

// Batched GEMM1 (chunk of 20 t): G = XT @ Wh^T via fp16x3 exact-split MFMA.
// K-loop: async global_load_lds double-buffer, ONE barrier per kc (m97 form).
__global__ __launch_bounds__(256, 2) void gemm1_mfma(
    const _Float16* __restrict__ Ahi, const _Float16* __restrict__ Alo,
    const _Float16* __restrict__ Bhi, const _Float16* __restrict__ Blo,
    float* __restrict__ G)
{
  __shared__ __align__(16) _Float16 lds[2][4][8][512];   // 64 KB, 2 blocks/CU
  const int tid = threadIdx.x, wave = tid>>6, lane = tid&63;
  const int bn = blockIdx.x, bm = blockIdx.y;
  const int wm = wave>>1, wn = wave&1;

  const _Float16* srcbase = (wave==0)?Ahi:(wave==1)?Alo:(wave==2)?Bhi:Blo;
  const int r16b = ((wave<2) ? bm : bn)*8;
  const _Float16* gsrc = srcbase + (size_t)r16b*32*512 + lane*8;

  f32x4 acc[16];
  #pragma unroll
  for (int i=0;i<16;i++) acc[i] = (f32x4){0.f,0.f,0.f,0.f};

  #pragma unroll
  for (int q=0;q<8;q++)
    gload_lds16(gsrc + (size_t)q*32*512, &lds[0][wave][q][0]);

  for (int kc=0;kc<32;kc++){
    __syncthreads();
    if (kc < 31){
      #pragma unroll
      for (int q=0;q<8;q++)
        gload_lds16(gsrc + ((size_t)q*32 + kc+1)*512, &lds[(kc+1)&1][wave][q][0]);
    }
    const int cb = kc&1;
    f16x8 fAh[4], fAl[4], fBh[4], fBl[4];
    #pragma unroll
    for (int i=0;i<4;i++){
      fAh[i] = *(const f16x8*)&lds[cb][0][wm*4+i][lane*8];
      fAl[i] = *(const f16x8*)&lds[cb][1][wm*4+i][lane*8];
      fBh[i] = *(const f16x8*)&lds[cb][2][wn*4+i][lane*8];
      fBl[i] = *(const f16x8*)&lds[cb][3][wn*4+i][lane*8];
    }
    #pragma unroll
    for (int i=0;i<4;i++)
      #pragma unroll
      for (int j=0;j<4;j++)
        acc[i*4+j] = __builtin_amdgcn_mfma_f32_16x16x32_f16(fAh[i], fBh[j], acc[i*4+j], 0,0,0);
    #pragma unroll
    for (int i=0;i<4;i++)
      #pragma unroll
      for (int j=0;j<4;j++)
        acc[i*4+j] = __builtin_amdgcn_mfma_f32_16x16x32_f16(fAh[i], fBl[j], acc[i*4+j], 0,0,0);
    #pragma unroll
    for (int i=0;i<4;i++)
      #pragma unroll
      for (int j=0;j<4;j++)
        acc[i*4+j] = __builtin_amdgcn_mfma_f32_16x16x32_f16(fAl[i], fBh[j], acc[i*4+j], 0,0,0);
  }
  const int colw = lane&15, quad = lane>>4;
  const float sc = 1.f/(2048.f*256.f);
  float* eds = (float*)lds + wave*2048;
  __syncthreads();
  #pragma unroll
  for (int ih=0; ih<2; ih++){
    #pragma unroll
    for (int il=0; il<2; il++){
      int i = ih*2+il;
      #pragma unroll
      for (int j=0;j<4;j++)
        #pragma unroll
        for (int r=0;r<4;r++)
          eds[(il*16 + quad*4 + r)*64 + j*16 + colw] = acc[i*4+j][r]*sc;
    }
    #pragma unroll
    for (int rr8=0; rr8<8; rr8++){
      int row = rr8*4 + quad;
      float4 v = *(float4*)&eds[row*64 + colw*4];
      int m = bm*128 + wm*64 + ih*32 + row;
      int n = bn*128 + wn*64 + colw*4;
      *(float4*)&G[(size_t)m*H_DIM + n] = v;
    }
  }
}

// Fused sequential step, 528 blocks:
//  blocks [0,512):  hv step t — emit hs_{t-1}, hv update, block max -> hmaxA[t+1]
//  blocks [512,528): ov step ovt = t-21 (its OG chunk is ready by stream order):
//                    apply spike of step ovt-1 (threshold from omaxA[ovt],
//                    finalized last launch), cnt++, ov += OG_ovt, block max
//                    -> atomicMax omaxA[ovt+1]. Runs on idle CUs, hidden.
__global__ __launch_bounds__(256) void hv_step(
    const float* __restrict__ Gs, float* __restrict__ hv,
    _Float16* __restrict__ hs_slot,
    const unsigned* __restrict__ hmax_t, unsigned* __restrict__ hmax_n, int t,
    const float* __restrict__ OG, float* __restrict__ ovs,
    uchar4* __restrict__ cnt8, unsigned* __restrict__ omaxA, int ovt)
{
  __shared__ float red[4];
  const int tid = threadIdx.x, lane = tid&63, wv = tid>>6;

  if (blockIdx.x < 512){
    if (t > T_STEPS) return;
    const int gid = blockIdx.x*256 + tid;     // 0..131071 (f4 index)
    const int b = gid >> 10, h0 = (gid & 1023) << 2;
    const float vth = vth_of(*hmax_t);
    float4 h = *(const float4*)(hv + (size_t)gid*4);

    if (t > 0){   // hs_{t-1} = hv_{t-1} > vth(max hv_{t-1})
      const int kc = h0>>5, kg=(h0>>3)&3, e=h0&7, r=b&15, m16l=b>>4;
      f16x4 s;
      s[0]=(h.x>vth)?(_Float16)1:(_Float16)0; s[1]=(h.y>vth)?(_Float16)1:(_Float16)0;
      s[2]=(h.z>vth)?(_Float16)1:(_Float16)0; s[3]=(h.w>vth)?(_Float16)1:(_Float16)0;
      *(f16x4*)(hs_slot + ((size_t)m16l*128 + kc)*512 + kg*128 + r*8 + e) = s;
    }
    if (t < T_STEPS){
      float4 g = *(const float4*)(Gs + (size_t)gid*4);
      float4 o;
      o.x = (h.x>vth ? 0.f : 0.5f*h.x) + g.x;
      o.y = (h.y>vth ? 0.f : 0.5f*h.y) + g.y;
      o.z = (h.z>vth ? 0.f : 0.5f*h.z) + g.z;
      o.w = (h.w>vth ? 0.f : 0.5f*h.w) + g.w;
      *(float4*)(hv + (size_t)gid*4) = o;
      float lmax = fmaxf(fmaxf(o.x,o.y),fmaxf(o.z,o.w));
      #pragma unroll
      for (int off=32; off>0; off>>=1) lmax = fmaxf(lmax, __shfl_down(lmax, off));
      if (lane==0) red[wv] = lmax;
      __syncthreads();
      if (tid==0){
        float m = fmaxf(fmaxf(red[0],red[1]),fmaxf(red[2],red[3]));
        atomicMax(hmax_n, fmap(m));
      }
    }
  } else {
    if (ovt < 0 || ovt > T_STEPS) return;
    const int f = (int)(blockIdx.x - 512)*256 + tid;   // f4 index 0..4095
    const float vthp = vth_of(omaxA[ovt]);             // max of step ovt-1
    float lmax = -3.0e38f;
    #pragma unroll
    for (int q=0;q<4;q++){
      int o4 = f + q*4096;
      float4 v = *(const float4*)(ovs + (size_t)o4*4);
      uchar4 c = cnt8[o4];
      bool s0 = v.x > vthp, s1 = v.y > vthp, s2 = v.z > vthp, s3 = v.w > vthp;
      c.x += s0; c.y += s1; c.z += s2; c.w += s3;
      v.x = s0 ? 0.f : 0.5f*v.x;
      v.y = s1 ? 0.f : 0.5f*v.y;
      v.z = s2 ? 0.f : 0.5f*v.z;
      v.w = s3 ? 0.f : 0.5f*v.w;
      if (ovt < T_STEPS){
        float4 g = *(const float4*)(OG + (size_t)ovt*(B_DIM*O_DIM) + (size_t)o4*4);
        v.x += g.x; v.y += g.y; v.z += g.z; v.w += g.w;
        lmax = fmaxf(lmax, fmaxf(fmaxf(v.x,v.y),fmaxf(v.z,v.w)));
      }
      *(float4*)(ovs + (size_t)o4*4) = v;
      cnt8[o4] = c;
    }
    if (ovt < T_STEPS){
      #pragma unroll
      for (int off=32; off>0; off>>=1) lmax = fmaxf(lmax, __shfl_down(lmax, off));
      if (lane==0) red[wv] = lmax;
      __syncthreads();
      if (tid==0){
        float m = fmaxf(fmaxf(red[0],red[1]),fmaxf(red[2],red[3]));
        atomicMax(&omaxA[ovt+1], fmap(m));
      }
    }
  }
}

// Batched GEMM2 for one chunk: OG[s] = HS[s] @ Wo^T (A exact f16, B hi/lo).
__global__ __launch_bounds__(256) void gemm2_mfma(
    const _Float16* __restrict__ HS,
    const _Float16* __restrict__ WoHi, const _Float16* __restrict__ WoLo,
    float* __restrict__ OG, int c)
{
  __shared__ float eds[4][2048];
  const int tid = threadIdx.x, wave = tid>>6, lane = tid&63;
  const int bn = blockIdx.x, bm = blockIdx.y;
  const int s = c*T_CHUNK + bm, ring = s % HS_RING;
  const int wm = wave>>1, wn = wave&1;

  const _Float16* Ab  = HS + ((size_t)(ring*8 + wm*4)*128)*512 + lane*8;
  const _Float16* Bhb = WoHi + ((size_t)(bn*8 + wn*4)*128)*512 + lane*8;
  const _Float16* Blb = WoLo + ((size_t)(bn*8 + wn*4)*128)*512 + lane*8;

  f32x4 acc[16];
  #pragma unroll
  for (int i=0;i<16;i++) acc[i] = (f32x4){0.f,0.f,0.f,0.f};

  int4 ra[4], rh[4], rl[4];
  #pragma unroll
  for (int q=0;q<4;q++){
    ra[q] = *(const int4*)(Ab  + (size_t)q*128*512);
    rh[q] = *(const int4*)(Bhb + (size_t)q*128*512);
    rl[q] = *(const int4*)(Blb + (size_t)q*128*512);
  }
  for (int kc=0;kc<128;kc++){
    f16x8 fA[4], fH[4], fL[4];
    #pragma unroll
    for (int q=0;q<4;q++){
      fA[q] = *(f16x8*)&ra[q]; fH[q] = *(f16x8*)&rh[q]; fL[q] = *(f16x8*)&rl[q];
    }
    if (kc < 127){
      #pragma unroll
      for (int q=0;q<4;q++){
        ra[q] = *(const int4*)(Ab  + ((size_t)q*128 + kc+1)*512);
        rh[q] = *(const int4*)(Bhb + ((size_t)q*128 + kc+1)*512);
        rl[q] = *(const int4*)(Blb + ((size_t)q*128 + kc+1)*512);
      }
    }
    #pragma unroll
    for (int i=0;i<4;i++)
      #pragma unroll
      for (int j=0;j<4;j++)
        acc[i*4+j] = __builtin_amdgcn_mfma_f32_16x16x32_f16(fA[i], fH[j], acc[i*4+j], 0,0,0);
    #pragma unroll
    for (int i=0;i<4;i++)
      #pragma unroll
      for (int j=0;j<4;j++)
        acc[i*4+j] = __builtin_amdgcn_mfma_f32_16x16x32_f16(fA[i], fL[j], acc[i*4+j], 0,0,0);
  }
  const int colw = lane&15, quad = lane>>4;
  const float sc = 1.f/256.f;
  #pragma unroll
  for (int ih=0; ih<2; ih++){
    #pragma unroll
    for (int il=0; il<2; il++){
      int i = ih*2+il;
      #pragma unroll
      for (int j=0;j<4;j++)
        #pragma unroll
        for (int r=0;r<4;r++)
          eds[wave][(il*16 + quad*4 + r)*64 + j*16 + colw] = acc[i*4+j][r]*sc;
    }
    #pragma unroll
    for (int rr8=0; rr8<8; rr8++){
      int row = rr8*4 + quad;
      float4 v = *(float4*)&eds[wave][row*64 + colw*4];
      int m = s*128 + wm*64 + ih*32 + row;
      int n = bn*128 + wn*64 + colw*4;
      *(float4*)&OG[(size_t)m*O_DIM + n] = v;
    }
  }
}

// out[o] = (float)cnt8[o]
__global__ __launch_bounds__(256) void cnt_to_out(const uchar4* __restrict__ cnt8,
                                                  float* __restrict__ out)
{
  int f = blockIdx.x*256 + threadIdx.x;   // 0..16383
  uchar4 c = cnt8[f];
  *(float4*)(out + (size_t)f*4) =
      make_float4((float)c.x, (float)c.y, (float)c.z, (float)c.w);
}

extern "C" void kernel_launch(void* const* d_in, const int* in_sizes, int n_in,
                              void* d_out, int out_size, void* d_ws, size_t ws_size,
                              hipStream_t stream) {
  const float* spike = (const float*)d_in[0];
  const float* Wh    = (const float*)d_in[5];   // [H, I]
  const float* Wo    = (const float*)d_in[6];   // [O, H]
  float* out = (float*)d_out;

  char* ws = (char*)d_ws;
  size_t off = 0;
  _Float16* XAhi = (_Float16*)(ws+off); off += (size_t)T_CHUNK*B_DIM*I_DIM*2;
  _Float16* XAlo = (_Float16*)(ws+off); off += (size_t)T_CHUNK*B_DIM*I_DIM*2;
  _Float16* WHhi = (_Float16*)(ws+off); off += (size_t)H_DIM*I_DIM*2;
  _Float16* WHlo = (_Float16*)(ws+off); off += (size_t)H_DIM*I_DIM*2;
  _Float16* WOhi = (_Float16*)(ws+off); off += (size_t)O_DIM*H_DIM*2;
  _Float16* WOlo = (_Float16*)(ws+off); off += (size_t)O_DIM*H_DIM*2;
  float* G  = (float*)(ws+off);         off += (size_t)T_CHUNK*B_DIM*H_DIM*4;
  float* hv = (float*)(ws+off);         off += (size_t)B_DIM*H_DIM*4;
  _Float16* HS = (_Float16*)(ws+off);   off += (size_t)HS_RING*HS_SLOT*2;
  float* OG = (float*)(ws+off);         off += (size_t)T_STEPS*B_DIM*O_DIM*4;
  float* ovs = (float*)(ws+off);        off += (size_t)B_DIM*O_DIM*4;
  uchar4* cnt8 = (uchar4*)(ws+off);     off += (size_t)B_DIM*O_DIM;
  unsigned* hmaxA = (unsigned*)(ws+off); off += 128*4;
  unsigned* omaxA = (unsigned*)(ws+off); off += 128*4;
  (void)ws_size; (void)in_sizes; (void)n_in; (void)out_size;

  init_kernel<<<(B_DIM*H_DIM+255)/256, 256, 0, stream>>>(
      hv, ovs, (uint32_t*)cnt8, hmaxA, omaxA);
  prep_weights<<<288, 256, 0, stream>>>(Wh, Wo, WHhi, WHlo, WOhi, WOlo);

  for (int c = 0; c < T_STEPS/T_CHUNK; c++){
    prep_x<<<dim3(8,32,2), 256, 0, stream>>>(spike, XAhi, XAlo, c*T_CHUNK);
    gemm1_mfma<<<dim3(32, T_CHUNK), 256, 0, stream>>>(XAhi, XAlo, WHhi, WHlo, G);
    for (int j = 0; j < T_CHUNK; j++){
      int t = c*T_CHUNK + j;
      int ring = (t == 0) ? (HS_RING-1) : ((t-1) % HS_RING);
      hv_step<<<528, 256, 0, stream>>>(
          G + (size_t)j*B_DIM*H_DIM, hv, HS + (size_t)ring*HS_SLOT,
          hmaxA + t, hmaxA + t + 1, t,
          OG, ovs, cnt8, omaxA, t - OV_LAG);
      if (j == 0 && c > 0)
        gemm2_mfma<<<dim3(4, T_CHUNK), 256, 0, stream>>>(HS, WOhi, WOlo, OG, c-1);
    }
  }
  // Tail: hs_99 emit (t=100), last gemm2 chunk, then drain remaining ov steps
  // (ovt = 80..100) on pure-ov launches (hv blocks no-op for t>100).
  hv_step<<<528, 256, 0, stream>>>(
      G, hv, HS + (size_t)((T_STEPS-1) % HS_RING)*HS_SLOT,
      hmaxA + T_STEPS, hmaxA + T_STEPS, T_STEPS,
      OG, ovs, cnt8, omaxA, T_STEPS - OV_LAG);
  gemm2_mfma<<<dim3(4, T_CHUNK), 256, 0, stream>>>(HS, WOhi, WOlo, OG, T_STEPS/T_CHUNK - 1);
  for (int t = T_STEPS + 1; t <= T_STEPS + OV_LAG; t++){
    hv_step<<<528, 256, 0, stream>>>(
        G, hv, HS,
        hmaxA + T_STEPS, hmaxA + T_STEPS, t,      // hv blocks: inert (t > T_STEPS)
        OG, ovs, cnt8, omaxA, t - OV_LAG);
  }
  cnt_to_out<<<64, 256, 0, stream>>>(cnt8, out);
}

// Round 11
// 1781.835 us; speedup vs baseline: 1.3304x; 1.1385x over previous
//
#include <hip/hip_runtime.h>
#include <math.h>
#include <stdint.h>

#define T_STEPS 100
#define B_DIM 128
#define I_DIM 1024
#define H_DIM 4096
#define O_DIM 512
#define T_CHUNK 20
#define HS_RING 21
#define HS_SLOT ((size_t)8*128*512)   // f16 per t-slot (8 m16-tiles x 128 kc x 512)
#define OV_LAG 21                     // ov step t' rides on hv launch t = t'+21

typedef _Float16 f16x8 __attribute__((ext_vector_type(8)));
typedef _Float16 f16x4 __attribute__((ext_vector_type(4)));
typedef float    f32x4 __attribute__((ext_vector_type(4)));

#define AS1 __attribute__((address_space(1)))
#define AS3 __attribute__((address_space(3)))

// Async global->LDS, 16B/lane. LDS dest is wave-uniform base + lane*16,
// which exactly matches the 1KB fragment-block layout (64 lanes x 16B).
__device__ __forceinline__ void gload_lds16(const _Float16* g, _Float16* l){
  __builtin_amdgcn_global_load_lds(
      (const AS1 unsigned*)(uintptr_t)g,
      (AS3 unsigned*)(unsigned)(uintptr_t)l, 16, 0, 0);
}

__device__ __forceinline__ unsigned fmap(float f){
  unsigned u = __float_as_uint(f);
  return (u & 0x80000000u) ? ~u : (u | 0x80000000u);
}
__device__ __forceinline__ float funmap(unsigned m){
  unsigned u = (m & 0x80000000u) ? (m & 0x7FFFFFFFu) : ~m;
  return __uint_as_float(u);
}
__device__ __forceinline__ float vth_of(unsigned m){
  return 0.3f * tanhf(0.3f * funmap(m));
}

__global__ __launch_bounds__(256) void init_kernel(float* hv, float* ovs,
                                                   uint32_t* cnt32,
                                                   unsigned* hmaxA, unsigned* omaxA)
{
  int i = blockIdx.x * 256 + threadIdx.x;
  if (i < B_DIM*H_DIM) hv[i] = 0.f;
  if (i < B_DIM*O_DIM) ovs[i] = 0.f;
  if (i < B_DIM*O_DIM/4) cnt32[i] = 0u;
  if (i < 128){
    // slot0 = "max of zero state" -> 0 -> vth 0 -> spike(0>0)=0
    unsigned v = (i==0) ? 0x80000000u : fmap(-3.0e38f);
    hmaxA[i] = v; omaxA[i] = v;
  }
}

// spike_data [B][I][T] fp32 -> fragment-tiled f16 hi/lo of (x*2048), chunk of 20 t.
__global__ __launch_bounds__(256) void prep_x(const float* __restrict__ sp,
                                              _Float16* __restrict__ Ahi,
                                              _Float16* __restrict__ Alo, int t0)
{
  __shared__ float tile[32][16][10];
  const int b16 = blockIdx.x, kc = blockIdx.y, tz = blockIdx.z;
  for (int e = threadIdx.x; e < 5120; e += 256){
    int tt = e % 10, row = e / 10;
    int bb = row >> 5, ii = row & 31;
    tile[ii][bb][tt] =
      sp[((size_t)(b16*16+bb)*I_DIM + kc*32 + ii)*T_STEPS + t0 + tz*10 + tt];
  }
  __syncthreads();
  for (int u = threadIdx.x; u < 640; u += 256){
    int tl = u >> 6, l = u & 63, kg = l >> 4, r = l & 15;
    f16x8 hi, lo;
    #pragma unroll
    for (int e=0;e<8;e++){
      float x = tile[kg*8+e][r][tl] * 2048.f;
      _Float16 h = (_Float16)x;
      hi[e] = h;
      lo[e] = (_Float16)(x - (float)h);
    }
    int t_local = tz*10 + tl;
    size_t off = ((size_t)(t_local*8 + b16)*32 + kc)*512 + kg*128 + r*8;
    *(f16x8*)(Ahi + off) = hi;
    *(f16x8*)(Alo + off) = lo;
  }
}

// Wh [H][I] and Wo [O][H] fp32 -> FB-tiled f16 hi/lo of (w*256), one launch.
__global__ __launch_bounds__(256) void prep_weights(
    const float* __restrict__ Wh, const float* __restrict__ Wo,
    _Float16* __restrict__ WHhi, _Float16* __restrict__ WHlo,
    _Float16* __restrict__ WOhi, _Float16* __restrict__ WOlo)
{
  const int blk = blockIdx.x;
  if (blk < 256){
    const int n16 = blk;
    for (int u = threadIdx.x; u < 2048; u += 256){
      int kc = u >> 6, l = u & 63, kg = l >> 4, r = l & 15;
      const float* src = Wh + (size_t)(n16*16 + r)*I_DIM + kc*32 + kg*8;
      f16x8 hi, lo;
      #pragma unroll
      for (int e=0;e<8;e++){
        float x = src[e] * 256.f;
        _Float16 h = (_Float16)x;
        hi[e] = h; lo[e] = (_Float16)(x - (float)h);
      }
      size_t off = ((size_t)n16*32 + kc)*512 + kg*128 + r*8;
      *(f16x8*)(WHhi + off) = hi;
      *(f16x8*)(WHlo + off) = lo;
    }
  } else {
    const int n16 = blk - 256;
    for (int u = threadIdx.x; u < 8192; u += 256){
      int kc = u >> 6, l = u & 63, kg = l >> 4, r = l & 15;
      const float* src = Wo + (size_t)(n16*16 + r)*H_DIM + kc*32 + kg*8;
      f16x8 hi, lo;
      #pragma unroll
      for (int e=0;e<8;e++){
        float x = src[e] * 256.f;
        _Float16 h = (_Float16)x;
        hi[e] = h; lo[e] = (_Float16)(x - (float)h);
      }
      size_t off = ((size_t)(n16*128 + kc))*512 + kg*128 + r*8;
      *(f16x8*)(WOhi + off) = hi;
      *(f16x8*)(WOlo + off) = lo;
    }
  }
}

// Batched GEMM1 (chunk of 20 t): G = XT @ Wh^T via fp16x3 exact-split MFMA.
// K-loop: async global_load_lds double-buffer, ONE barrier per kc (m97 form).
__global__ __launch_bounds__(256, 2) void gemm1_mfma(
    const _Float16* __restrict__ Ahi, const _Float16* __restrict__ Alo,
    const _Float16* __restrict__ Bhi, const _Float16* __restrict__ Blo,
    float* __restrict__ G)
{
  __shared__ __align__(16) _Float16 lds[2][4][8][512];   // 64 KB, 2 blocks/CU
  const int tid = threadIdx.x, wave = tid>>6, lane = tid&63;
  const int bn = blockIdx.x, bm = blockIdx.y;
  const int wm = wave>>1, wn = wave&1;

  const _Float16* srcbase = (wave==0)?Ahi:(wave==1)?Alo:(wave==2)?Bhi:Blo;
  const int r16b = ((wave<2) ? bm : bn)*8;
  const _Float16* gsrc = srcbase + (size_t)r16b*32*512 + lane*8;

  f32x4 acc[16];
  #pragma unroll
  for (int i=0;i<16;i++) acc[i] = (f32x4){0.f,0.f,0.f,0.f};

  #pragma unroll
  for (int q=0;q<8;q++)
    gload_lds16(gsrc + (size_t)q*32*512, &lds[0][wave][q][0]);

  for (int kc=0;kc<32;kc++){
    __syncthreads();
    if (kc < 31){
      #pragma unroll
      for (int q=0;q<8;q++)
        gload_lds16(gsrc + ((size_t)q*32 + kc+1)*512, &lds[(kc+1)&1][wave][q][0]);
    }
    const int cb = kc&1;
    f16x8 fAh[4], fAl[4], fBh[4], fBl[4];
    #pragma unroll
    for (int i=0;i<4;i++){
      fAh[i] = *(const f16x8*)&lds[cb][0][wm*4+i][lane*8];
      fAl[i] = *(const f16x8*)&lds[cb][1][wm*4+i][lane*8];
      fBh[i] = *(const f16x8*)&lds[cb][2][wn*4+i][lane*8];
      fBl[i] = *(const f16x8*)&lds[cb][3][wn*4+i][lane*8];
    }
    #pragma unroll
    for (int i=0;i<4;i++)
      #pragma unroll
      for (int j=0;j<4;j++)
        acc[i*4+j] = __builtin_amdgcn_mfma_f32_16x16x32_f16(fAh[i], fBh[j], acc[i*4+j], 0,0,0);
    #pragma unroll
    for (int i=0;i<4;i++)
      #pragma unroll
      for (int j=0;j<4;j++)
        acc[i*4+j] = __builtin_amdgcn_mfma_f32_16x16x32_f16(fAh[i], fBl[j], acc[i*4+j], 0,0,0);
    #pragma unroll
    for (int i=0;i<4;i++)
      #pragma unroll
      for (int j=0;j<4;j++)
        acc[i*4+j] = __builtin_amdgcn_mfma_f32_16x16x32_f16(fAl[i], fBh[j], acc[i*4+j], 0,0,0);
  }
  const int colw = lane&15, quad = lane>>4;
  const float sc = 1.f/(2048.f*256.f);
  float* eds = (float*)lds + wave*2048;
  __syncthreads();
  #pragma unroll
  for (int ih=0; ih<2; ih++){
    #pragma unroll
    for (int il=0; il<2; il++){
      int i = ih*2+il;
      #pragma unroll
      for (int j=0;j<4;j++)
        #pragma unroll
        for (int r=0;r<4;r++)
          eds[(il*16 + quad*4 + r)*64 + j*16 + colw] = acc[i*4+j][r]*sc;
    }
    #pragma unroll
    for (int rr8=0; rr8<8; rr8++){
      int row = rr8*4 + quad;
      float4 v = *(float4*)&eds[row*64 + colw*4];
      int m = bm*128 + wm*64 + ih*32 + row;
      int n = bn*128 + wn*64 + colw*4;
      *(float4*)&G[(size_t)m*H_DIM + n] = v;
    }
  }
}

// Fused sequential step, 528 blocks:
//  blocks [0,512):  hv step t — emit hs_{t-1}, hv update, block max -> hmaxA[t+1]
//  blocks [512,528): ov step ovt = t-21: spike of ovt-1, cnt++, ov += OG halves,
//                    block max -> atomicMax omaxA[ovt+1]. Hidden on idle CUs.
__global__ __launch_bounds__(256) void hv_step(
    const float* __restrict__ Gs, float* __restrict__ hv,
    _Float16* __restrict__ hs_slot,
    const unsigned* __restrict__ hmax_t, unsigned* __restrict__ hmax_n, int t,
    const float* __restrict__ OGp, float* __restrict__ ovs,
    uchar4* __restrict__ cnt8, unsigned* __restrict__ omaxA, int ovt)
{
  __shared__ float red[4];
  const int tid = threadIdx.x, lane = tid&63, wv = tid>>6;

  if (blockIdx.x < 512){
    if (t > T_STEPS) return;
    const int gid = blockIdx.x*256 + tid;     // 0..131071 (f4 index)
    const int b = gid >> 10, h0 = (gid & 1023) << 2;
    const float vth = vth_of(*hmax_t);
    float4 h = *(const float4*)(hv + (size_t)gid*4);

    if (t > 0){   // hs_{t-1} = hv_{t-1} > vth(max hv_{t-1})
      const int kc = h0>>5, kg=(h0>>3)&3, e=h0&7, r=b&15, m16l=b>>4;
      f16x4 s;
      s[0]=(h.x>vth)?(_Float16)1:(_Float16)0; s[1]=(h.y>vth)?(_Float16)1:(_Float16)0;
      s[2]=(h.z>vth)?(_Float16)1:(_Float16)0; s[3]=(h.w>vth)?(_Float16)1:(_Float16)0;
      *(f16x4*)(hs_slot + ((size_t)m16l*128 + kc)*512 + kg*128 + r*8 + e) = s;
    }
    if (t < T_STEPS){
      float4 g = *(const float4*)(Gs + (size_t)gid*4);
      float4 o;
      o.x = (h.x>vth ? 0.f : 0.5f*h.x) + g.x;
      o.y = (h.y>vth ? 0.f : 0.5f*h.y) + g.y;
      o.z = (h.z>vth ? 0.f : 0.5f*h.z) + g.z;
      o.w = (h.w>vth ? 0.f : 0.5f*h.w) + g.w;
      *(float4*)(hv + (size_t)gid*4) = o;
      float lmax = fmaxf(fmaxf(o.x,o.y),fmaxf(o.z,o.w));
      #pragma unroll
      for (int off=32; off>0; off>>=1) lmax = fmaxf(lmax, __shfl_down(lmax, off));
      if (lane==0) red[wv] = lmax;
      __syncthreads();
      if (tid==0){
        float m = fmaxf(fmaxf(red[0],red[1]),fmaxf(red[2],red[3]));
        atomicMax(hmax_n, fmap(m));
      }
    }
  } else {
    if (ovt < 0 || ovt > T_STEPS) return;
    const int f = (int)(blockIdx.x - 512)*256 + tid;   // f4 index 0..4095
    const float vthp = vth_of(omaxA[ovt]);             // max of step ovt-1
    float lmax = -3.0e38f;
    #pragma unroll
    for (int q=0;q<4;q++){
      int o4 = f + q*4096;
      float4 v = *(const float4*)(ovs + (size_t)o4*4);
      uchar4 c = cnt8[o4];
      bool s0 = v.x > vthp, s1 = v.y > vthp, s2 = v.z > vthp, s3 = v.w > vthp;
      c.x += s0; c.y += s1; c.z += s2; c.w += s3;
      v.x = s0 ? 0.f : 0.5f*v.x;
      v.y = s1 ? 0.f : 0.5f*v.y;
      v.z = s2 ? 0.f : 0.5f*v.z;
      v.w = s3 ? 0.f : 0.5f*v.w;
      if (ovt < T_STEPS){
        float4 ga = *(const float4*)(OGp + (size_t)ovt*(B_DIM*O_DIM) + (size_t)o4*4);
        float4 gb = *(const float4*)(OGp + ((size_t)T_STEPS + ovt)*(B_DIM*O_DIM) + (size_t)o4*4);
        v.x += ga.x + gb.x; v.y += ga.y + gb.y;
        v.z += ga.z + gb.z; v.w += ga.w + gb.w;
        lmax = fmaxf(lmax, fmaxf(fmaxf(v.x,v.y),fmaxf(v.z,v.w)));
      }
      *(float4*)(ovs + (size_t)o4*4) = v;
      cnt8[o4] = c;
    }
    if (ovt < T_STEPS){
      #pragma unroll
      for (int off=32; off>0; off>>=1) lmax = fmaxf(lmax, __shfl_down(lmax, off));
      if (lane==0) red[wv] = lmax;
      __syncthreads();
      if (tid==0){
        float m = fmaxf(fmaxf(red[0],red[1]),fmaxf(red[2],red[3]));
        atomicMax(&omaxA[ovt+1], fmap(m));
      }
    }
  }
}

// Batched GEMM2 v2: OGp[kh][s] = HS[s] @ Wo^T over K-half kh (A exact f16,
// B hi/lo). gemm1-style async-LDS double buffer: per kc-slab 24 FBs
// (A 8, Bhi 8, Blo 8 = 24KB), 6 gload_lds16 per wave, one barrier per kc.
// Grid (4, 20, 2) = 160 blocks; 2-way K-split halves per-block serial latency.
__global__ __launch_bounds__(256, 2) void gemm2_mfma(
    const _Float16* __restrict__ HS,
    const _Float16* __restrict__ WoHi, const _Float16* __restrict__ WoLo,
    float* __restrict__ OGp, int c)
{
  __shared__ __align__(16) _Float16 lds2[2][24][512];   // 48 KB
  const int tid = threadIdx.x, wave = tid>>6, lane = tid&63;
  const int bn = blockIdx.x, bm = blockIdx.y, kh = blockIdx.z;
  const int s = c*T_CHUNK + bm, ring = s % HS_RING;
  const int wm = wave>>1, wn = wave&1;
  const int kc0 = kh*64;

  const _Float16* baseA = HS   + (size_t)ring*8*128*512 + lane*8;
  const _Float16* baseH = WoHi + (size_t)bn*8*128*512 + lane*8;
  const _Float16* baseL = WoLo + (size_t)bn*8*128*512 + lane*8;

  f32x4 acc[16];
  #pragma unroll
  for (int i=0;i<16;i++) acc[i] = (f32x4){0.f,0.f,0.f,0.f};

  // stage kc0 into buffer 0: wave w stages FBs f = w*6 .. w*6+5
  #pragma unroll
  for (int i=0;i<6;i++){
    int f = wave*6 + i;
    const _Float16* g = (f<8)  ? baseA + ((size_t)f*128      + kc0)*512
                     : (f<16) ? baseH + ((size_t)(f-8)*128  + kc0)*512
                              : baseL + ((size_t)(f-16)*128 + kc0)*512;
    gload_lds16(g, &lds2[0][f][0]);
  }

  for (int k=0;k<64;k++){
    __syncthreads();              // vmcnt drain + barrier: buf[k&1] ready
    if (k < 63){
      #pragma unroll
      for (int i=0;i<6;i++){
        int f = wave*6 + i;
        const _Float16* g = (f<8)  ? baseA + ((size_t)f*128      + kc0+k+1)*512
                         : (f<16) ? baseH + ((size_t)(f-8)*128  + kc0+k+1)*512
                                  : baseL + ((size_t)(f-16)*128 + kc0+k+1)*512;
        gload_lds16(g, &lds2[(k+1)&1][f][0]);
      }
    }
    const int cb = k&1;
    f16x8 fA[4], fH[4], fL[4];
    #pragma unroll
    for (int i=0;i<4;i++){
      fA[i] = *(const f16x8*)&lds2[cb][wm*4+i][lane*8];
      fH[i] = *(const f16x8*)&lds2[cb][8+wn*4+i][lane*8];
      fL[i] = *(const f16x8*)&lds2[cb][16+wn*4+i][lane*8];
    }
    #pragma unroll
    for (int i=0;i<4;i++)
      #pragma unroll
      for (int j=0;j<4;j++)
        acc[i*4+j] = __builtin_amdgcn_mfma_f32_16x16x32_f16(fA[i], fH[j], acc[i*4+j], 0,0,0);
    #pragma unroll
    for (int i=0;i<4;i++)
      #pragma unroll
      for (int j=0;j<4;j++)
        acc[i*4+j] = __builtin_amdgcn_mfma_f32_16x16x32_f16(fA[i], fL[j], acc[i*4+j], 0,0,0);
  }
  const int colw = lane&15, quad = lane>>4;
  const float sc = 1.f/256.f;
  float* eds = (float*)lds2 + wave*2048;
  __syncthreads();
  float* OGd = OGp + ((size_t)kh*T_STEPS + s)*(B_DIM*O_DIM);
  #pragma unroll
  for (int ih=0; ih<2; ih++){
    #pragma unroll
    for (int il=0; il<2; il++){
      int i = ih*2+il;
      #pragma unroll
      for (int j=0;j<4;j++)
        #pragma unroll
        for (int r=0;r<4;r++)
          eds[(il*16 + quad*4 + r)*64 + j*16 + colw] = acc[i*4+j][r]*sc;
    }
    #pragma unroll
    for (int rr8=0; rr8<8; rr8++){
      int row = rr8*4 + quad;
      float4 v = *(float4*)&eds[row*64 + colw*4];
      int m = wm*64 + ih*32 + row;
      int n = bn*128 + wn*64 + colw*4;
      *(float4*)&OGd[(size_t)m*O_DIM + n] = v;
    }
  }
}

// out[o] = (float)cnt8[o]
__global__ __launch_bounds__(256) void cnt_to_out(const uchar4* __restrict__ cnt8,
                                                  float* __restrict__ out)
{
  int f = blockIdx.x*256 + threadIdx.x;   // 0..16383
  uchar4 c = cnt8[f];
  *(float4*)(out + (size_t)f*4) =
      make_float4((float)c.x, (float)c.y, (float)c.z, (float)c.w);
}

extern "C" void kernel_launch(void* const* d_in, const int* in_sizes, int n_in,
                              void* d_out, int out_size, void* d_ws, size_t ws_size,
                              hipStream_t stream) {
  const float* spike = (const float*)d_in[0];
  const float* Wh    = (const float*)d_in[5];   // [H, I]
  const float* Wo    = (const float*)d_in[6];   // [O, H]
  float* out = (float*)d_out;

  char* ws = (char*)d_ws;
  size_t off = 0;
  _Float16* XAhi = (_Float16*)(ws+off); off += (size_t)T_CHUNK*B_DIM*I_DIM*2;
  _Float16* XAlo = (_Float16*)(ws+off); off += (size_t)T_CHUNK*B_DIM*I_DIM*2;
  _Float16* WHhi = (_Float16*)(ws+off); off += (size_t)H_DIM*I_DIM*2;
  _Float16* WHlo = (_Float16*)(ws+off); off += (size_t)H_DIM*I_DIM*2;
  _Float16* WOhi = (_Float16*)(ws+off); off += (size_t)O_DIM*H_DIM*2;
  _Float16* WOlo = (_Float16*)(ws+off); off += (size_t)O_DIM*H_DIM*2;
  float* G  = (float*)(ws+off);         off += (size_t)T_CHUNK*B_DIM*H_DIM*4;
  float* hv = (float*)(ws+off);         off += (size_t)B_DIM*H_DIM*4;
  _Float16* HS = (_Float16*)(ws+off);   off += (size_t)HS_RING*HS_SLOT*2;
  float* OGp = (float*)(ws+off);        off += (size_t)2*T_STEPS*B_DIM*O_DIM*4;
  float* ovs = (float*)(ws+off);        off += (size_t)B_DIM*O_DIM*4;
  uchar4* cnt8 = (uchar4*)(ws+off);     off += (size_t)B_DIM*O_DIM;
  unsigned* hmaxA = (unsigned*)(ws+off); off += 128*4;
  unsigned* omaxA = (unsigned*)(ws+off); off += 128*4;
  (void)ws_size; (void)in_sizes; (void)n_in; (void)out_size;

  init_kernel<<<(B_DIM*H_DIM+255)/256, 256, 0, stream>>>(
      hv, ovs, (uint32_t*)cnt8, hmaxA, omaxA);
  prep_weights<<<288, 256, 0, stream>>>(Wh, Wo, WHhi, WHlo, WOhi, WOlo);

  for (int c = 0; c < T_STEPS/T_CHUNK; c++){
    prep_x<<<dim3(8,32,2), 256, 0, stream>>>(spike, XAhi, XAlo, c*T_CHUNK);
    gemm1_mfma<<<dim3(32, T_CHUNK), 256, 0, stream>>>(XAhi, XAlo, WHhi, WHlo, G);
    for (int j = 0; j < T_CHUNK; j++){
      int t = c*T_CHUNK + j;
      int ring = (t == 0) ? (HS_RING-1) : ((t-1) % HS_RING);
      hv_step<<<528, 256, 0, stream>>>(
          G + (size_t)j*B_DIM*H_DIM, hv, HS + (size_t)ring*HS_SLOT,
          hmaxA + t, hmaxA + t + 1, t,
          OGp, ovs, cnt8, omaxA, t - OV_LAG);
      if (j == 0 && c > 0)
        gemm2_mfma<<<dim3(4, T_CHUNK, 2), 256, 0, stream>>>(HS, WOhi, WOlo, OGp, c-1);
    }
  }
  // Tail: hs_99 emit (t=100), last gemm2 chunk, then drain remaining ov steps
  // (ovt = 80..100) on pure-ov launches (hv blocks no-op for t>100).
  hv_step<<<528, 256, 0, stream>>>(
      G, hv, HS + (size_t)((T_STEPS-1) % HS_RING)*HS_SLOT,
      hmaxA + T_STEPS, hmaxA + T_STEPS, T_STEPS,
      OGp, ovs, cnt8, omaxA, T_STEPS - OV_LAG);
  gemm2_mfma<<<dim3(4, T_CHUNK, 2), 256, 0, stream>>>(HS, WOhi, WOlo, OGp, T_STEPS/T_CHUNK - 1);
  for (int t = T_STEPS + 1; t <= T_STEPS + OV_LAG; t++){
    hv_step<<<528, 256, 0, stream>>>(
        G, hv, HS,
        hmaxA + T_STEPS, hmaxA + T_STEPS, t,      // hv blocks: inert (t > T_STEPS)
        OGp, ovs, cnt8, omaxA, t - OV_LAG);
  }
  cnt_to_out<<<64, 256, 0, stream>>>(cnt8, out);
}

// Round 12
// 1649.371 us; speedup vs baseline: 1.4372x; 1.0803x over previous
//
#include <hip/hip_runtime.h>
#include <math.h>
#include <stdint.h>

#define T_STEPS 100
#define B_DIM 128
#define I_DIM 1024
#define H_DIM 4096
#define O_DIM 512
#define T_CHUNK 20
#define HS_RING 21
#define HS_SLOT ((size_t)8*128*512)   // f16 per t-slot (8 m16-tiles x 128 kc x 512)
#define OV_LAG 21                     // ov step t' rides on hv launch t = t'+21
#define RING_S 40                     // OG partial ring: 40 t-slots x 4 K-planes
#define TAIL_START 80                 // ov steps >= 80 handled by ov_tail

typedef _Float16 f16x8 __attribute__((ext_vector_type(8)));
typedef _Float16 f16x4 __attribute__((ext_vector_type(4)));
typedef float    f32x4 __attribute__((ext_vector_type(4)));

#define AS1 __attribute__((address_space(1)))
#define AS3 __attribute__((address_space(3)))

// Async global->LDS, 16B/lane. LDS dest is wave-uniform base + lane*16,
// which exactly matches the 1KB fragment-block layout (64 lanes x 16B).
__device__ __forceinline__ void gload_lds16(const _Float16* g, _Float16* l){
  __builtin_amdgcn_global_load_lds(
      (const AS1 unsigned*)(uintptr_t)g,
      (AS3 unsigned*)(unsigned)(uintptr_t)l, 16, 0, 0);
}

__device__ __forceinline__ unsigned fmap(float f){
  unsigned u = __float_as_uint(f);
  return (u & 0x80000000u) ? ~u : (u | 0x80000000u);
}
__device__ __forceinline__ float funmap(unsigned m){
  unsigned u = (m & 0x80000000u) ? (m & 0x7FFFFFFFu) : ~m;
  return __uint_as_float(u);
}
__device__ __forceinline__ float vth_of(unsigned m){
  return 0.3f * tanhf(0.3f * funmap(m));
}

__global__ __launch_bounds__(256) void init_kernel(float* hv, float* ovs,
                                                   uint32_t* cnt32,
                                                   unsigned* hmaxA, unsigned* omaxA,
                                                   unsigned* gctr)
{
  int i = blockIdx.x * 256 + threadIdx.x;
  if (i < B_DIM*H_DIM) hv[i] = 0.f;
  if (i < B_DIM*O_DIM) ovs[i] = 0.f;
  if (i < B_DIM*O_DIM/4) cnt32[i] = 0u;
  if (i == 0) gctr[0] = 0u;
  if (i < 128){
    // slot0 = "max of zero state" -> 0 -> vth 0 -> spike(0>0)=0
    unsigned v = (i==0) ? 0x80000000u : fmap(-3.0e38f);
    hmaxA[i] = v; omaxA[i] = v;
  }
}

// spike_data [B][I][T] fp32 -> fragment-tiled f16 hi/lo of (x*2048), chunk of 20 t.
__global__ __launch_bounds__(256) void prep_x(const float* __restrict__ sp,
                                              _Float16* __restrict__ Ahi,
                                              _Float16* __restrict__ Alo, int t0)
{
  __shared__ float tile[32][16][10];
  const int b16 = blockIdx.x, kc = blockIdx.y, tz = blockIdx.z;
  for (int e = threadIdx.x; e < 5120; e += 256){
    int tt = e % 10, row = e / 10;
    int bb = row >> 5, ii = row & 31;
    tile[ii][bb][tt] =
      sp[((size_t)(b16*16+bb)*I_DIM + kc*32 + ii)*T_STEPS + t0 + tz*10 + tt];
  }
  __syncthreads();
  for (int u = threadIdx.x; u < 640; u += 256){
    int tl = u >> 6, l = u & 63, kg = l >> 4, r = l & 15;
    f16x8 hi, lo;
    #pragma unroll
    for (int e=0;e<8;e++){
      float x = tile[kg*8+e][r][tl] * 2048.f;
      _Float16 h = (_Float16)x;
      hi[e] = h;
      lo[e] = (_Float16)(x - (float)h);
    }
    int t_local = tz*10 + tl;
    size_t off = ((size_t)(t_local*8 + b16)*32 + kc)*512 + kg*128 + r*8;
    *(f16x8*)(Ahi + off) = hi;
    *(f16x8*)(Alo + off) = lo;
  }
}

// Wh [H][I] and Wo [O][H] fp32 -> FB-tiled f16 hi/lo of (w*256), one launch.
__global__ __launch_bounds__(256) void prep_weights(
    const float* __restrict__ Wh, const float* __restrict__ Wo,
    _Float16* __restrict__ WHhi, _Float16* __restrict__ WHlo,
    _Float16* __restrict__ WOhi, _Float16* __restrict__ WOlo)
{
  const int blk = blockIdx.x;
  if (blk < 256){
    const int n16 = blk;
    for (int u = threadIdx.x; u < 2048; u += 256){
      int kc = u >> 6, l = u & 63, kg = l >> 4, r = l & 15;
      const float* src = Wh + (size_t)(n16*16 + r)*I_DIM + kc*32 + kg*8;
      f16x8 hi, lo;
      #pragma unroll
      for (int e=0;e<8;e++){
        float x = src[e] * 256.f;
        _Float16 h = (_Float16)x;
        hi[e] = h; lo[e] = (_Float16)(x - (float)h);
      }
      size_t off = ((size_t)n16*32 + kc)*512 + kg*128 + r*8;
      *(f16x8*)(WHhi + off) = hi;
      *(f16x8*)(WHlo + off) = lo;
    }
  } else {
    const int n16 = blk - 256;
    for (int u = threadIdx.x; u < 8192; u += 256){
      int kc = u >> 6, l = u & 63, kg = l >> 4, r = l & 15;
      const float* src = Wo + (size_t)(n16*16 + r)*H_DIM + kc*32 + kg*8;
      f16x8 hi, lo;
      #pragma unroll
      for (int e=0;e<8;e++){
        float x = src[e] * 256.f;
        _Float16 h = (_Float16)x;
        hi[e] = h; lo[e] = (_Float16)(x - (float)h);
      }
      size_t off = ((size_t)(n16*128 + kc))*512 + kg*128 + r*8;
      *(f16x8*)(WOhi + off) = hi;
      *(f16x8*)(WOlo + off) = lo;
    }
  }
}

// Batched GEMM1 (chunk of 20 t): G = XT @ Wh^T via fp16x3 exact-split MFMA.
// K-loop: async global_load_lds double-buffer, ONE barrier per kc (m97 form).
__global__ __launch_bounds__(256, 2) void gemm1_mfma(
    const _Float16* __restrict__ Ahi, const _Float16* __restrict__ Alo,
    const _Float16* __restrict__ Bhi, const _Float16* __restrict__ Blo,
    float* __restrict__ G)
{
  __shared__ __align__(16) _Float16 lds[2][4][8][512];   // 64 KB, 2 blocks/CU
  const int tid = threadIdx.x, wave = tid>>6, lane = tid&63;
  const int bn = blockIdx.x, bm = blockIdx.y;
  const int wm = wave>>1, wn = wave&1;

  const _Float16* srcbase = (wave==0)?Ahi:(wave==1)?Alo:(wave==2)?Bhi:Blo;
  const int r16b = ((wave<2) ? bm : bn)*8;
  const _Float16* gsrc = srcbase + (size_t)r16b*32*512 + lane*8;

  f32x4 acc[16];
  #pragma unroll
  for (int i=0;i<16;i++) acc[i] = (f32x4){0.f,0.f,0.f,0.f};

  #pragma unroll
  for (int q=0;q<8;q++)
    gload_lds16(gsrc + (size_t)q*32*512, &lds[0][wave][q][0]);

  for (int kc=0;kc<32;kc++){
    __syncthreads();
    if (kc < 31){
      #pragma unroll
      for (int q=0;q<8;q++)
        gload_lds16(gsrc + ((size_t)q*32 + kc+1)*512, &lds[(kc+1)&1][wave][q][0]);
    }
    const int cb = kc&1;
    f16x8 fAh[4], fAl[4], fBh[4], fBl[4];
    #pragma unroll
    for (int i=0;i<4;i++){
      fAh[i] = *(const f16x8*)&lds[cb][0][wm*4+i][lane*8];
      fAl[i] = *(const f16x8*)&lds[cb][1][wm*4+i][lane*8];
      fBh[i] = *(const f16x8*)&lds[cb][2][wn*4+i][lane*8];
      fBl[i] = *(const f16x8*)&lds[cb][3][wn*4+i][lane*8];
    }
    #pragma unroll
    for (int i=0;i<4;i++)
      #pragma unroll
      for (int j=0;j<4;j++)
        acc[i*4+j] = __builtin_amdgcn_mfma_f32_16x16x32_f16(fAh[i], fBh[j], acc[i*4+j], 0,0,0);
    #pragma unroll
    for (int i=0;i<4;i++)
      #pragma unroll
      for (int j=0;j<4;j++)
        acc[i*4+j] = __builtin_amdgcn_mfma_f32_16x16x32_f16(fAh[i], fBl[j], acc[i*4+j], 0,0,0);
    #pragma unroll
    for (int i=0;i<4;i++)
      #pragma unroll
      for (int j=0;j<4;j++)
        acc[i*4+j] = __builtin_amdgcn_mfma_f32_16x16x32_f16(fAl[i], fBh[j], acc[i*4+j], 0,0,0);
  }
  const int colw = lane&15, quad = lane>>4;
  const float sc = 1.f/(2048.f*256.f);
  float* eds = (float*)lds + wave*2048;
  __syncthreads();
  #pragma unroll
  for (int ih=0; ih<2; ih++){
    #pragma unroll
    for (int il=0; il<2; il++){
      int i = ih*2+il;
      #pragma unroll
      for (int j=0;j<4;j++)
        #pragma unroll
        for (int r=0;r<4;r++)
          eds[(il*16 + quad*4 + r)*64 + j*16 + colw] = acc[i*4+j][r]*sc;
    }
    #pragma unroll
    for (int rr8=0; rr8<8; rr8++){
      int row = rr8*4 + quad;
      float4 v = *(float4*)&eds[row*64 + colw*4];
      int m = bm*128 + wm*64 + ih*32 + row;
      int n = bn*128 + wn*64 + colw*4;
      *(float4*)&G[(size_t)m*H_DIM + n] = v;
    }
  }
}

// Fused sequential step, 528 blocks:
//  blocks [0,512):  hv step t — emit hs_{t-1}, hv update, block max -> hmaxA[t+1]
//  blocks [512,528): ov step ovt = t-21 (< TAIL_START): spike of ovt-1, cnt++,
//                    ov += 4 OG K-planes, block max -> atomicMax omaxA[ovt+1].
__global__ __launch_bounds__(256) void hv_step(
    const float* __restrict__ Gs, float* __restrict__ hv,
    _Float16* __restrict__ hs_slot,
    const unsigned* __restrict__ hmax_t, unsigned* __restrict__ hmax_n, int t,
    const float* __restrict__ OGp, float* __restrict__ ovs,
    uchar4* __restrict__ cnt8, unsigned* __restrict__ omaxA, int ovt)
{
  __shared__ float red[4];
  const int tid = threadIdx.x, lane = tid&63, wv = tid>>6;

  if (blockIdx.x < 512){
    if (t > T_STEPS) return;
    const int gid = blockIdx.x*256 + tid;     // 0..131071 (f4 index)
    const int b = gid >> 10, h0 = (gid & 1023) << 2;
    const float vth = vth_of(*hmax_t);
    float4 h = *(const float4*)(hv + (size_t)gid*4);

    if (t > 0){   // hs_{t-1} = hv_{t-1} > vth(max hv_{t-1})
      const int kc = h0>>5, kg=(h0>>3)&3, e=h0&7, r=b&15, m16l=b>>4;
      f16x4 s;
      s[0]=(h.x>vth)?(_Float16)1:(_Float16)0; s[1]=(h.y>vth)?(_Float16)1:(_Float16)0;
      s[2]=(h.z>vth)?(_Float16)1:(_Float16)0; s[3]=(h.w>vth)?(_Float16)1:(_Float16)0;
      *(f16x4*)(hs_slot + ((size_t)m16l*128 + kc)*512 + kg*128 + r*8 + e) = s;
    }
    if (t < T_STEPS){
      float4 g = *(const float4*)(Gs + (size_t)gid*4);
      float4 o;
      o.x = (h.x>vth ? 0.f : 0.5f*h.x) + g.x;
      o.y = (h.y>vth ? 0.f : 0.5f*h.y) + g.y;
      o.z = (h.z>vth ? 0.f : 0.5f*h.z) + g.z;
      o.w = (h.w>vth ? 0.f : 0.5f*h.w) + g.w;
      *(float4*)(hv + (size_t)gid*4) = o;
      float lmax = fmaxf(fmaxf(o.x,o.y),fmaxf(o.z,o.w));
      #pragma unroll
      for (int off=32; off>0; off>>=1) lmax = fmaxf(lmax, __shfl_down(lmax, off));
      if (lane==0) red[wv] = lmax;
      __syncthreads();
      if (tid==0){
        float m = fmaxf(fmaxf(red[0],red[1]),fmaxf(red[2],red[3]));
        atomicMax(hmax_n, fmap(m));
      }
    }
  } else {
    if (ovt < 0 || ovt >= TAIL_START) return;
    const int f = (int)(blockIdx.x - 512)*256 + tid;   // f4 index 0..4095
    const float vthp = vth_of(omaxA[ovt]);             // max of step ovt-1
    const int slot = ovt % RING_S;
    float lmax = -3.0e38f;
    #pragma unroll
    for (int q=0;q<4;q++){
      int o4 = f + q*4096;
      float4 v = *(const float4*)(ovs + (size_t)o4*4);
      uchar4 c = cnt8[o4];
      bool s0 = v.x > vthp, s1 = v.y > vthp, s2 = v.z > vthp, s3 = v.w > vthp;
      c.x += s0; c.y += s1; c.z += s2; c.w += s3;
      v.x = s0 ? 0.f : 0.5f*v.x;
      v.y = s1 ? 0.f : 0.5f*v.y;
      v.z = s2 ? 0.f : 0.5f*v.z;
      v.w = s3 ? 0.f : 0.5f*v.w;
      float4 g0 = *(const float4*)(OGp + ((size_t)slot*4+0)*(B_DIM*O_DIM) + (size_t)o4*4);
      float4 g1 = *(const float4*)(OGp + ((size_t)slot*4+1)*(B_DIM*O_DIM) + (size_t)o4*4);
      float4 g2 = *(const float4*)(OGp + ((size_t)slot*4+2)*(B_DIM*O_DIM) + (size_t)o4*4);
      float4 g3 = *(const float4*)(OGp + ((size_t)slot*4+3)*(B_DIM*O_DIM) + (size_t)o4*4);
      v.x += (g0.x+g1.x)+(g2.x+g3.x);
      v.y += (g0.y+g1.y)+(g2.y+g3.y);
      v.z += (g0.z+g1.z)+(g2.z+g3.z);
      v.w += (g0.w+g1.w)+(g2.w+g3.w);
      lmax = fmaxf(lmax, fmaxf(fmaxf(v.x,v.y),fmaxf(v.z,v.w)));
      *(float4*)(ovs + (size_t)o4*4) = v;
      cnt8[o4] = c;
    }
    #pragma unroll
    for (int off=32; off>0; off>>=1) lmax = fmaxf(lmax, __shfl_down(lmax, off));
    if (lane==0) red[wv] = lmax;
    __syncthreads();
    if (tid==0){
      float m = fmaxf(fmaxf(red[0],red[1]),fmaxf(red[2],red[3]));
      atomicMax(&omaxA[ovt+1], fmap(m));
    }
  }
}

// Batched GEMM2 v3: 4-way K-split. OGp[(s%RING_S)*4 + kh] = HS[s] @ Wo^T over
// K-quarter kh. gemm1-style async-LDS double buffer: per kc-slab 24 FBs
// (A 8, Bhi 8, Blo 8 = 24KB), 6 gload_lds16 per wave, one barrier per kc.
// Grid (4, 20, 4) = 320 blocks: per-block serial K halved vs v2, grid > #CU.
__global__ __launch_bounds__(256, 2) void gemm2_mfma(
    const _Float16* __restrict__ HS,
    const _Float16* __restrict__ WoHi, const _Float16* __restrict__ WoLo,
    float* __restrict__ OGp, int c)
{
  __shared__ __align__(16) _Float16 lds2[2][24][512];   // 48 KB
  const int tid = threadIdx.x, wave = tid>>6, lane = tid&63;
  const int bn = blockIdx.x, bm = blockIdx.y, kh = blockIdx.z;
  const int s = c*T_CHUNK + bm, ring = s % HS_RING;
  const int wm = wave>>1, wn = wave&1;
  const int kc0 = kh*32;

  const _Float16* baseA = HS   + (size_t)ring*8*128*512 + lane*8;
  const _Float16* baseH = WoHi + (size_t)bn*8*128*512 + lane*8;
  const _Float16* baseL = WoLo + (size_t)bn*8*128*512 + lane*8;

  f32x4 acc[16];
  #pragma unroll
  for (int i=0;i<16;i++) acc[i] = (f32x4){0.f,0.f,0.f,0.f};

  // stage kc0 into buffer 0: wave w stages FBs f = w*6 .. w*6+5
  #pragma unroll
  for (int i=0;i<6;i++){
    int f = wave*6 + i;
    const _Float16* g = (f<8)  ? baseA + ((size_t)f*128      + kc0)*512
                     : (f<16) ? baseH + ((size_t)(f-8)*128  + kc0)*512
                              : baseL + ((size_t)(f-16)*128 + kc0)*512;
    gload_lds16(g, &lds2[0][f][0]);
  }

  for (int k=0;k<32;k++){
    __syncthreads();              // vmcnt drain + barrier: buf[k&1] ready
    if (k < 31){
      #pragma unroll
      for (int i=0;i<6;i++){
        int f = wave*6 + i;
        const _Float16* g = (f<8)  ? baseA + ((size_t)f*128      + kc0+k+1)*512
                         : (f<16) ? baseH + ((size_t)(f-8)*128  + kc0+k+1)*512
                                  : baseL + ((size_t)(f-16)*128 + kc0+k+1)*512;
        gload_lds16(g, &lds2[(k+1)&1][f][0]);
      }
    }
    const int cb = k&1;
    f16x8 fA[4], fH[4], fL[4];
    #pragma unroll
    for (int i=0;i<4;i++){
      fA[i] = *(const f16x8*)&lds2[cb][wm*4+i][lane*8];
      fH[i] = *(const f16x8*)&lds2[cb][8+wn*4+i][lane*8];
      fL[i] = *(const f16x8*)&lds2[cb][16+wn*4+i][lane*8];
    }
    #pragma unroll
    for (int i=0;i<4;i++)
      #pragma unroll
      for (int j=0;j<4;j++)
        acc[i*4+j] = __builtin_amdgcn_mfma_f32_16x16x32_f16(fA[i], fH[j], acc[i*4+j], 0,0,0);
    #pragma unroll
    for (int i=0;i<4;i++)
      #pragma unroll
      for (int j=0;j<4;j++)
        acc[i*4+j] = __builtin_amdgcn_mfma_f32_16x16x32_f16(fA[i], fL[j], acc[i*4+j], 0,0,0);
  }
  const int colw = lane&15, quad = lane>>4;
  const float sc = 1.f/256.f;
  float* eds = (float*)lds2 + wave*2048;
  __syncthreads();
  float* OGd = OGp + ((size_t)(s % RING_S)*4 + kh)*(B_DIM*O_DIM);
  #pragma unroll
  for (int ih=0; ih<2; ih++){
    #pragma unroll
    for (int il=0; il<2; il++){
      int i = ih*2+il;
      #pragma unroll
      for (int j=0;j<4;j++)
        #pragma unroll
        for (int r=0;r<4;r++)
          eds[(il*16 + quad*4 + r)*64 + j*16 + colw] = acc[i*4+j][r]*sc;
    }
    #pragma unroll
    for (int rr8=0; rr8<8; rr8++){
      int row = rr8*4 + quad;
      float4 v = *(float4*)&eds[row*64 + colw*4];
      int m = wm*64 + ih*32 + row;
      int n = bn*128 + wn*64 + colw*4;
      *(float4*)&OGd[(size_t)m*O_DIM + n] = v;
    }
  }
}

// Tail: ov steps TAIL_START..T_STEPS in ONE 16-block persistent kernel.
// ov/cnt state in registers (16 elem/thread); per step: spike/decay, add 4 OG
// planes, block max -> atomicMax omaxA[ovt+1], 16-block monotonic barrier.
// Writes out directly at the end (replaces cnt_to_out).
__global__ __launch_bounds__(256) void ov_tail(
    const float* __restrict__ OGp, const float* __restrict__ ovs,
    const uchar4* __restrict__ cnt8, unsigned* __restrict__ omaxA,
    unsigned* __restrict__ gctr, float* __restrict__ out)
{
  __shared__ float red[4];
  const int tid = threadIdx.x, lane = tid&63, wv = tid>>6;
  const int f = blockIdx.x*256 + tid;
  float ov[16];
  unsigned cw[4];          // byte-packed counts per 4-group
  #pragma unroll
  for (int q=0;q<4;q++){
    int o4 = f + q*4096;
    float4 v = *(const float4*)(ovs + (size_t)o4*4);
    ov[q*4+0]=v.x; ov[q*4+1]=v.y; ov[q*4+2]=v.z; ov[q*4+3]=v.w;
    uchar4 c = cnt8[o4];
    cw[q] = (unsigned)c.x | ((unsigned)c.y<<8) | ((unsigned)c.z<<16) | ((unsigned)c.w<<24);
  }
  unsigned bar = 0;

  for (int ovt = TAIL_START; ovt <= T_STEPS; ovt++){
    const float vth = vth_of(omaxA[ovt]);
    const int slot = ovt % RING_S;
    float lmax = -3.0e38f;
    #pragma unroll
    for (int q=0;q<4;q++){
      int o4 = f + q*4096;
      #pragma unroll
      for (int e=0;e<4;e++){
        int idx = q*4+e;
        bool os = ov[idx] > vth;
        cw[q] += os ? (1u<<(e*8)) : 0u;
        ov[idx] = os ? 0.f : 0.5f*ov[idx];
      }
      if (ovt < T_STEPS){
        float4 g0 = *(const float4*)(OGp + ((size_t)slot*4+0)*(B_DIM*O_DIM) + (size_t)o4*4);
        float4 g1 = *(const float4*)(OGp + ((size_t)slot*4+1)*(B_DIM*O_DIM) + (size_t)o4*4);
        float4 g2 = *(const float4*)(OGp + ((size_t)slot*4+2)*(B_DIM*O_DIM) + (size_t)o4*4);
        float4 g3 = *(const float4*)(OGp + ((size_t)slot*4+3)*(B_DIM*O_DIM) + (size_t)o4*4);
        ov[q*4+0] += (g0.x+g1.x)+(g2.x+g3.x);
        ov[q*4+1] += (g0.y+g1.y)+(g2.y+g3.y);
        ov[q*4+2] += (g0.z+g1.z)+(g2.z+g3.z);
        ov[q*4+3] += (g0.w+g1.w)+(g2.w+g3.w);
        lmax = fmaxf(lmax, fmaxf(fmaxf(ov[q*4+0],ov[q*4+1]),fmaxf(ov[q*4+2],ov[q*4+3])));
      }
    }
    if (ovt == T_STEPS) break;    // last step: spike-only, no sync needed
    #pragma unroll
    for (int off=32; off>0; off>>=1) lmax = fmaxf(lmax, __shfl_down(lmax, off));
    if (lane==0) red[wv] = lmax;
    __syncthreads();
    // 16-block monotonic barrier; tid0 publishes block max first.
    if (tid==0){
      float m = fmaxf(fmaxf(red[0],red[1]),fmaxf(red[2],red[3]));
      atomicMax(&omaxA[ovt+1], fmap(m));
      __threadfence();
      atomicAdd(gctr, 1u);
      unsigned target = (++bar)*16;
      while (__hip_atomic_load(gctr, __ATOMIC_RELAXED, __HIP_MEMORY_SCOPE_AGENT) < target)
        __builtin_amdgcn_s_sleep(1);
      __threadfence();
    }
    __syncthreads();
    if (tid!=0) bar++;            // keep bar consistent across threads
  }
  #pragma unroll
  for (int q=0;q<4;q++){
    int o4 = f + q*4096;
    *(float4*)(out + (size_t)o4*4) = make_float4(
        (float)( cw[q]        & 0xffu),
        (float)((cw[q] >> 8)  & 0xffu),
        (float)((cw[q] >> 16) & 0xffu),
        (float)((cw[q] >> 24) & 0xffu));
  }
}

extern "C" void kernel_launch(void* const* d_in, const int* in_sizes, int n_in,
                              void* d_out, int out_size, void* d_ws, size_t ws_size,
                              hipStream_t stream) {
  const float* spike = (const float*)d_in[0];
  const float* Wh    = (const float*)d_in[5];   // [H, I]
  const float* Wo    = (const float*)d_in[6];   // [O, H]
  float* out = (float*)d_out;

  char* ws = (char*)d_ws;
  size_t off = 0;
  _Float16* XAhi = (_Float16*)(ws+off); off += (size_t)T_CHUNK*B_DIM*I_DIM*2;
  _Float16* XAlo = (_Float16*)(ws+off); off += (size_t)T_CHUNK*B_DIM*I_DIM*2;
  _Float16* WHhi = (_Float16*)(ws+off); off += (size_t)H_DIM*I_DIM*2;
  _Float16* WHlo = (_Float16*)(ws+off); off += (size_t)H_DIM*I_DIM*2;
  _Float16* WOhi = (_Float16*)(ws+off); off += (size_t)O_DIM*H_DIM*2;
  _Float16* WOlo = (_Float16*)(ws+off); off += (size_t)O_DIM*H_DIM*2;
  float* G  = (float*)(ws+off);         off += (size_t)T_CHUNK*B_DIM*H_DIM*4;
  float* hv = (float*)(ws+off);         off += (size_t)B_DIM*H_DIM*4;
  _Float16* HS = (_Float16*)(ws+off);   off += (size_t)HS_RING*HS_SLOT*2;
  float* OGp = (float*)(ws+off);        off += (size_t)RING_S*4*B_DIM*O_DIM*4;
  float* ovs = (float*)(ws+off);        off += (size_t)B_DIM*O_DIM*4;
  uchar4* cnt8 = (uchar4*)(ws+off);     off += (size_t)B_DIM*O_DIM;
  unsigned* hmaxA = (unsigned*)(ws+off); off += 128*4;
  unsigned* omaxA = (unsigned*)(ws+off); off += 128*4;
  unsigned* gctr  = (unsigned*)(ws+off); off += 64*4;
  (void)ws_size; (void)in_sizes; (void)n_in; (void)out_size;

  init_kernel<<<(B_DIM*H_DIM+255)/256, 256, 0, stream>>>(
      hv, ovs, (uint32_t*)cnt8, hmaxA, omaxA, gctr);
  prep_weights<<<288, 256, 0, stream>>>(Wh, Wo, WHhi, WHlo, WOhi, WOlo);

  for (int c = 0; c < T_STEPS/T_CHUNK; c++){
    prep_x<<<dim3(8,32,2), 256, 0, stream>>>(spike, XAhi, XAlo, c*T_CHUNK);
    gemm1_mfma<<<dim3(32, T_CHUNK), 256, 0, stream>>>(XAhi, XAlo, WHhi, WHlo, G);
    for (int j = 0; j < T_CHUNK; j++){
      int t = c*T_CHUNK + j;
      int ring = (t == 0) ? (HS_RING-1) : ((t-1) % HS_RING);
      hv_step<<<528, 256, 0, stream>>>(
          G + (size_t)j*B_DIM*H_DIM, hv, HS + (size_t)ring*HS_SLOT,
          hmaxA + t, hmaxA + t + 1, t,
          OGp, ovs, cnt8, omaxA, t - OV_LAG);
      if (j == 0 && c > 0)
        gemm2_mfma<<<dim3(4, T_CHUNK, 4), 256, 0, stream>>>(HS, WOhi, WOlo, OGp, c-1);
    }
  }
  // Tail: hs_99 emit (t=100, rider ovt=79 = last main rider), final gemm2
  // chunk, then the persistent 16-block ov_tail (ovt = 80..100) + direct out.
  hv_step<<<528, 256, 0, stream>>>(
      G, hv, HS + (size_t)((T_STEPS-1) % HS_RING)*HS_SLOT,
      hmaxA + T_STEPS, hmaxA + T_STEPS, T_STEPS,
      OGp, ovs, cnt8, omaxA, T_STEPS - OV_LAG);
  gemm2_mfma<<<dim3(4, T_CHUNK, 4), 256, 0, stream>>>(HS, WOhi, WOlo, OGp, T_STEPS/T_CHUNK - 1);
  ov_tail<<<16, 256, 0, stream>>>(OGp, ovs, cnt8, omaxA, gctr, out);
}